// Round 8
// baseline (34.083 us; speedup 1.0000x reference)
//
#include <hip/hip_runtime.h>
#include <math.h>

#define NB 512
#define HW 169
#define NA 5
#define NCH 125
#define BLOCK 256
#define NBLOCKS ((NB * HW) / BLOCK)   // 338
#define REC 8                          // padded per-block record (dwords)

// R3-config main kernel (best so far). Launched TWICE this round (idempotent)
// to measure per-launch steady-state cost M directly: dur_R8 - dur_R3 = M.
__global__ __launch_bounds__(BLOCK, 2) void yolo_loss_main(
    const float* __restrict__ P,    // [B][125][169] (channel-major)
    const float* __restrict__ T,    // [B][169][125]
    const float* __restrict__ ANC,  // [5][2]
    float* __restrict__ brec)       // [NBLOCKS][REC]
{
    int t = threadIdx.x;
    int idx = blockIdx.x * BLOCK + t;
    int b  = idx / HW;
    int hw = idx - b * HW;

    const float* Pb = P + (size_t)b * NCH * HW + hw;
    const float* Tb = T + ((size_t)b * HW + hw) * NCH;

    // ---- phase 1: all 45 independent loads first
    float gx[NA], gy[NA], gw_[NA], gh[NA], gc[NA];
    float rx[NA], ry[NA], rw[NA], rh[NA];
#pragma unroll
    for (int a = 0; a < NA; ++a) {
        int c0 = a * 25;
        gc[a]  = Tb[c0 + 20];
        gx[a]  = Tb[c0 + 21];
        gy[a]  = Tb[c0 + 22];
        gw_[a] = Tb[c0 + 23];
        gh[a]  = Tb[c0 + 24];
    }
#pragma unroll
    for (int a = 0; a < NA; ++a) {
        int c0 = a * 25;
        rx[a] = Pb[(c0 + 21) * HW];
        ry[a] = Pb[(c0 + 22) * HW];
        rw[a] = Pb[(c0 + 23) * HW];
        rh[a] = Pb[(c0 + 24) * HW];
    }

    // ---- phase 2: transforms
    float px[NA], py[NA], pw[NA], ph[NA];
#pragma unroll
    for (int a = 0; a < NA; ++a) {
        px[a] = 1.0f / (1.0f + expf(-rx[a]));
        py[a] = 1.0f / (1.0f + expf(-ry[a]));
        pw[a] = expf(rw[a]);
        ph[a] = expf(rh[a]);
    }

    float contrib[NA];
    int cmask = 0;
#pragma unroll
    for (int i = 0; i < NA; ++i) {
        float aw = ANC[2 * i], ah = ANC[2 * i + 1];
        float ax1 = px[i] - aw * 0.5f, ax2 = px[i] + aw * 0.5f;
        float ay1 = py[i] - ah * 0.5f, ay2 = py[i] + ah * 0.5f;
        float area_a = (ax2 - ax1) * (ay2 - ay1);
        float best = -1.0f; int bestj = 0;
#pragma unroll
        for (int j = 0; j < NA; ++j) {
            float bx1 = gx[j] - gw_[j] * 0.5f, bx2 = gx[j] + gw_[j] * 0.5f;
            float by1 = gy[j] - gh[j] * 0.5f, by2 = gy[j] + gh[j] * 0.5f;
            float iw = fmaxf(fminf(ax2, bx2) - fmaxf(ax1, bx1), 0.0f);
            float ih = fmaxf(fminf(ay2, by2) - fmaxf(ay1, by1), 0.0f);
            float inter = iw * ih;
            float area_b = (bx2 - bx1) * (by2 - by1);
            float iou = inter / (area_a + area_b - inter + 1e-10f);
            if (iou > best) { best = iou; bestj = j; }   // strict > == jnp.argmax first-max
        }
        cmask |= (1 << bestj);
        float dx = px[i] - gx[i], dy = py[i] - gy[i];
        float dw = pw[i] - gw_[i], dh = ph[i] - gh[i];
        contrib[i] = gc[i] * gc[i] * (dx * dx + dy * dy + dw * dw + dh * dh);
    }

    // ---- phase 3: wave shuffle reduce -> cross-wave via LDS -> 32-B record
    __shared__ float sred[4][NA];
    __shared__ int smask[4];
    int lane = t & 63, wid = t >> 6;

#pragma unroll
    for (int i = 0; i < NA; ++i) {
        float v = contrib[i];
        for (int off = 32; off; off >>= 1) v += __shfl_down(v, off, 64);
        if (lane == 0) sred[wid][i] = v;
    }
    for (int off = 32; off; off >>= 1) cmask |= __shfl_down(cmask, off, 64);
    if (lane == 0) smask[wid] = cmask;
    __syncthreads();

    if (t == 0) {
        int m = smask[0] | smask[1] | smask[2] | smask[3];
        float* r = brec + blockIdx.x * REC;
#pragma unroll
        for (int i = 0; i < NA; ++i)
            r[i] = sred[0][i] + sred[1][i] + sred[2][i] + sred[3][i];
        ((int*)r)[5] = m;
        ((int*)r)[6] = 0;
        ((int*)r)[7] = 0;
    }
}

__global__ void yolo_loss_final(const float* __restrict__ brec,
                                float* __restrict__ out)
{
    int lane = threadIdx.x;          // one 64-lane wave
    const float4* r4 = (const float4*)brec;
    double s[NA] = {0, 0, 0, 0, 0};
    int m = 0;
    for (int e = lane; e < NBLOCKS; e += 64) {
        float4 lo = r4[e * 2];
        float4 hi = r4[e * 2 + 1];
        s[0] += (double)lo.x; s[1] += (double)lo.y;
        s[2] += (double)lo.z; s[3] += (double)lo.w;
        s[4] += (double)hi.x;
        m |= __float_as_int(hi.y);
    }
#pragma unroll
    for (int i = 0; i < NA; ++i)
        for (int off = 32; off; off >>= 1) s[i] += __shfl_down(s[i], off, 64);
    for (int off = 32; off; off >>= 1) m |= __shfl_down(m, off, 64);

    if (lane == 0) {
        double tot = 0.0;
#pragma unroll
        for (int i = 0; i < NA; ++i)
            if ((m >> i) & 1) tot += s[i];
        out[0] = (float)((5.0 / 512.0) * tot);
    }
}

extern "C" void kernel_launch(void* const* d_in, const int* in_sizes, int n_in,
                              void* d_out, int out_size, void* d_ws, size_t ws_size,
                              hipStream_t stream) {
    const float* P   = (const float*)d_in[0];
    const float* T   = (const float*)d_in[1];
    const float* ANC = (const float*)d_in[2];
    float* out = (float*)d_out;

    float* brec = (float*)d_ws;   // NBLOCKS * REC floats

    // CALIBRATION: two identical idempotent main launches; delta vs R3 == M_steady.
    yolo_loss_main<<<NBLOCKS, BLOCK, 0, stream>>>(P, T, ANC, brec);
    yolo_loss_main<<<NBLOCKS, BLOCK, 0, stream>>>(P, T, ANC, brec);
    yolo_loss_final<<<1, 64, 0, stream>>>(brec, out);
}

// Round 9
// 20.214 us; speedup vs baseline: 1.6861x; 1.6861x over previous
//
#include <hip/hip_runtime.h>
#include <math.h>

#define NB 512
#define HW 169
#define NA 5
#define NCH 125
#define BLOCK 256
#define NPAIRS (NB * HW * NA)            // 432640 (cell,anchor) pairs
#define NBLOCKS (NPAIRS / BLOCK)         // 1690 exactly
#define REC 8                            // padded per-block record (dwords)

// One thread per (cell, anchor) pair: 5x the wave count of the per-cell version
// -> 26 waves/CU outstanding-load parallelism instead of 5.3. The 5 threads of
// a cell sit in adjacent lanes; their shared gt-box reads coalesce/broadcast.
__global__ __launch_bounds__(BLOCK, 4) void yolo_loss_main(
    const float* __restrict__ P,    // [B][125][169] (channel-major)
    const float* __restrict__ T,    // [B][169][125]
    const float* __restrict__ ANC,  // [5][2]
    float* __restrict__ brec)       // [NBLOCKS][REC]
{
    int t = threadIdx.x;
    int pid  = blockIdx.x * BLOCK + t;
    int cell = pid / NA;                 // 0..86527
    int a    = pid - cell * NA;          // own anchor slot 0..4
    int b  = cell / HW;
    int hw = cell - b * HW;

    const float* Tc = T + (size_t)cell * NCH;
    const float* Pb = P + (size_t)b * NCH * HW + hw;

    // ---- loads: 20 gt-box floats (compile-time offsets off one base) + own conf
    //      + own 4 prediction logits. All independent; issue together.
    float g[20];
#pragma unroll
    for (int j = 0; j < NA; ++j) {
        g[j * 4 + 0] = Tc[j * 25 + 21];
        g[j * 4 + 1] = Tc[j * 25 + 22];
        g[j * 4 + 2] = Tc[j * 25 + 23];
        g[j * 4 + 3] = Tc[j * 25 + 24];
    }
    float conf = Tc[a * 25 + 20];
    float rx = Pb[(a * 25 + 21) * HW];
    float ry = Pb[(a * 25 + 22) * HW];
    float rw = Pb[(a * 25 + 23) * HW];
    float rh = Pb[(a * 25 + 24) * HW];
    float aw = ANC[2 * a], ah = ANC[2 * a + 1];

    // ---- transforms (own anchor only)
    float px = 1.0f / (1.0f + expf(-rx));
    float py = 1.0f / (1.0f + expf(-ry));
    float pw = expf(rw);
    float ph = expf(rh);

    // ---- one IoU row: anchor-box(a) vs all 5 gt boxes; argmax with strict >
    float ax1 = px - aw * 0.5f, ax2 = px + aw * 0.5f;
    float ay1 = py - ah * 0.5f, ay2 = py + ah * 0.5f;
    float area_a = (ax2 - ax1) * (ay2 - ay1);
    float best = -1.0f; int bestj = 0;
    float gxa = 0.f, gya = 0.f, gwa = 0.f, gha = 0.f;  // own gt box via select (no runtime array idx)
#pragma unroll
    for (int j = 0; j < NA; ++j) {
        float bx = g[j * 4 + 0], by = g[j * 4 + 1];
        float bw = g[j * 4 + 2], bh = g[j * 4 + 3];
        float bx1 = bx - bw * 0.5f, bx2 = bx + bw * 0.5f;
        float by1 = by - bh * 0.5f, by2 = by + bh * 0.5f;
        float iw = fmaxf(fminf(ax2, bx2) - fmaxf(ax1, bx1), 0.0f);
        float ih = fmaxf(fminf(ay2, by2) - fmaxf(ay1, by1), 0.0f);
        float inter = iw * ih;
        float area_b = (bx2 - bx1) * (by2 - by1);
        float iou = inter / (area_a + area_b - inter + 1e-10f);
        if (iou > best) { best = iou; bestj = j; }     // first-max tie semantics
        if (j == a) { gxa = bx; gya = by; gwa = bw; gha = bh; }
    }
    int cmask = 1 << bestj;

    float dx = px - gxa, dy = py - gya, dw = pw - gwa, dh = ph - gha;
    float contrib = conf * conf * (dx * dx + dy * dy + dw * dw + dh * dh);

    // ---- reduce into 5 anchor bins (bin = own a), wave shuffle -> LDS -> record
    __shared__ float sred[4][NA];
    __shared__ int smask[4];
    int lane = t & 63, wid = t >> 6;

#pragma unroll
    for (int i = 0; i < NA; ++i) {
        float v = (a == i) ? contrib : 0.0f;
        for (int off = 32; off; off >>= 1) v += __shfl_down(v, off, 64);
        if (lane == 0) sred[wid][i] = v;
    }
    for (int off = 32; off; off >>= 1) cmask |= __shfl_down(cmask, off, 64);
    if (lane == 0) smask[wid] = cmask;
    __syncthreads();

    if (t == 0) {
        int m = smask[0] | smask[1] | smask[2] | smask[3];
        float4* r4 = (float4*)(brec + blockIdx.x * REC);
        r4[0] = make_float4(sred[0][0] + sred[1][0] + sred[2][0] + sred[3][0],
                            sred[0][1] + sred[1][1] + sred[2][1] + sred[3][1],
                            sred[0][2] + sred[1][2] + sred[2][2] + sred[3][2],
                            sred[0][3] + sred[1][3] + sred[2][3] + sred[3][3]);
        r4[1] = make_float4(sred[0][4] + sred[1][4] + sred[2][4] + sred[3][4],
                            __int_as_float(m), 0.0f, 0.0f);
    }
}

__global__ __launch_bounds__(256) void yolo_loss_final(
    const float* __restrict__ brec, float* __restrict__ out)
{
    __shared__ double sredd[4][NA];
    __shared__ int smaskd[4];
    int t = threadIdx.x, lane = t & 63, wid = t >> 6;
    const float4* r4 = (const float4*)brec;

    double s[NA] = {0, 0, 0, 0, 0};
    int m = 0;
    for (int e = t; e < NBLOCKS; e += 256) {
        float4 lo = r4[e * 2];
        float4 hi = r4[e * 2 + 1];
        s[0] += (double)lo.x; s[1] += (double)lo.y;
        s[2] += (double)lo.z; s[3] += (double)lo.w;
        s[4] += (double)hi.x;
        m |= __float_as_int(hi.y);
    }
#pragma unroll
    for (int i = 0; i < NA; ++i)
        for (int off = 32; off; off >>= 1) s[i] += __shfl_down(s[i], off, 64);
    for (int off = 32; off; off >>= 1) m |= __shfl_down(m, off, 64);
    if (lane == 0) {
#pragma unroll
        for (int i = 0; i < NA; ++i) sredd[wid][i] = s[i];
        smaskd[wid] = m;
    }
    __syncthreads();

    if (t == 0) {
        int mm = smaskd[0] | smaskd[1] | smaskd[2] | smaskd[3];
        double tot = 0.0;
#pragma unroll
        for (int i = 0; i < NA; ++i)
            if ((mm >> i) & 1)
                tot += sredd[0][i] + sredd[1][i] + sredd[2][i] + sredd[3][i];
        out[0] = (float)((5.0 / 512.0) * tot);
    }
}

extern "C" void kernel_launch(void* const* d_in, const int* in_sizes, int n_in,
                              void* d_out, int out_size, void* d_ws, size_t ws_size,
                              hipStream_t stream) {
    const float* P   = (const float*)d_in[0];
    const float* T   = (const float*)d_in[1];
    const float* ANC = (const float*)d_in[2];
    float* out = (float*)d_out;

    float* brec = (float*)d_ws;   // NBLOCKS * REC floats = 54 KB

    yolo_loss_main<<<NBLOCKS, BLOCK, 0, stream>>>(P, T, ANC, brec);
    yolo_loss_final<<<1, 256, 0, stream>>>(brec, out);
}